// Round 9
// baseline (292.923 us; speedup 1.0000x reference)
//
#include <hip/hip_runtime.h>

#define N_NODES 50000
#define N_EDGES 800000
#define NBUCK 196    // dst>>8 -> 0..195
#define NHIST 196    // histogram blocks (4096 edges each)

typedef __attribute__((ext_vector_type(8))) short short8;
typedef __attribute__((ext_vector_type(4))) float f32x4;
typedef __attribute__((ext_vector_type(4))) unsigned short ushort4v;
typedef __attribute__((ext_vector_type(8))) unsigned short ushort8v;
typedef __attribute__((ext_vector_type(16))) unsigned char uchar16;

// ---------------- split-bf16 helpers ----------------
// f32 = hi(bf16) + lo(bf16) + O(2^-33). Self path uses Ahi*Bhi+Ahi*Blo+Alo*Bhi;
// agg path gathers an int8+per-row-scale plane (R7): row = 128B (2 lines).

__device__ inline void split_bf16(float f, unsigned short& hi, unsigned short& lo) {
    union { float f; unsigned u; } a; a.f = f;
    unsigned r = (a.u + 0x7fffu + ((a.u >> 16) & 1u)) >> 16;  // RNE to bf16
    hi = (unsigned short)r;
    union { unsigned u; float f; } b; b.u = r << 16;
    union { float f; unsigned u; } c; c.f = f - b.f;
    unsigned r2 = (c.u + 0x7fffu + ((c.u >> 16) & 1u)) >> 16;
    lo = (unsigned short)r2;
}

__device__ inline unsigned short f2bf(float f) {
    union { float f; unsigned u; } a; a.f = f;
    return (unsigned short)((a.u + 0x7fffu + ((a.u >> 16) & 1u)) >> 16);
}

__device__ inline float bf2f(unsigned short u) {
    union { unsigned u; float f; } a; a.u = (unsigned)u << 16; return a.f;
}

__device__ inline unsigned char q8(float v, float qs) {
    int qi = (int)rintf(v * qs);
    qi = qi > 127 ? 127 : (qi < -127 ? -127 : qi);
    return (unsigned char)(qi + 128);
}

// accumulate 4 biased-u8 values (one dword) scaled by s into a[0..3]
__device__ inline void acc4(float* a, unsigned w, float s) {
#pragma unroll
    for (int j = 0; j < 4; ++j)
        a[j] += (float)((w >> (8 * j)) & 255u) * s;
}

// ---------------- prep: pack(W) + split/quantize(x) + bucket histogram -------

__global__ void prep_kernel(const float* __restrict__ W0, const float* __restrict__ W1,
                            const float* __restrict__ W2, const float* __restrict__ W3,
                            const float* __restrict__ W4, const float* __restrict__ W5,
                            unsigned short* __restrict__ wout,
                            const float* __restrict__ x, unsigned short* __restrict__ xhi,
                            unsigned short* __restrict__ xlo,
                            unsigned char* __restrict__ xq, float* __restrict__ xsc,
                            const int* __restrict__ dst, int* __restrict__ blkhist) {
    __shared__ int lhist[NBUCK];
    if (blockIdx.x < 320) {
        int t = blockIdx.x * 256 + threadIdx.x;  // 0..81919
        const float* W; int D, local, half; size_t base;
        if (t < 65536) {
            int mat = t >> 14; local = t & 16383; D = 128; half = 16384;
            base = (size_t)mat * 32768;
            W = mat == 0 ? W0 : mat == 1 ? W1 : mat == 2 ? W2 : W3;
        } else {
            int m = (t - 65536) >> 13; local = (t - 65536) & 8191; D = 64; half = 8192;
            base = 131072 + (size_t)m * 16384;
            W = m == 0 ? W4 : W5;
        }
        int j = local & 7, lane = (local >> 3) & 63, ks = (local >> 9) & 3, ct = local >> 11;
        int k = ks * 32 + ((lane >> 4) << 3) + j;
        int n = (ct << 4) + (lane & 15);
        unsigned short hi, lo;
        split_bf16(W[k * D + n], hi, lo);
        wout[base + local] = hi;
        wout[base + half + local] = lo;
    } else if (blockIdx.x < 1883) {
        int t = (blockIdx.x - 320) * 256 + threadIdx.x;  // one 16-float chunk/thread
        if (t >= N_NODES * 8) return;                    // 50000*128/16 = 400000
        const float* p = x + (size_t)t * 16;
        float4 v0 = *(const float4*)(p);
        float4 v1 = *(const float4*)(p + 4);
        float4 v2 = *(const float4*)(p + 8);
        float4 v3 = *(const float4*)(p + 12);
        float vv[16] = {v0.x, v0.y, v0.z, v0.w, v1.x, v1.y, v1.z, v1.w,
                        v2.x, v2.y, v2.z, v2.w, v3.x, v3.y, v3.z, v3.w};
        // rowmax over 128 floats: 8 consecutive threads share a row (aligned)
        float m = 0.f;
#pragma unroll
        for (int j = 0; j < 16; ++j) m = fmaxf(m, fabsf(vv[j]));
        m = fmaxf(m, __shfl_xor(m, 1));
        m = fmaxf(m, __shfl_xor(m, 2));
        m = fmaxf(m, __shfl_xor(m, 4));
        float qs = m > 0.f ? 127.0f / m : 0.0f;
        uchar16 qv;
        ushort8v h0, l0, h1, l1;
#pragma unroll
        for (int j = 0; j < 16; ++j) {
            unsigned short a, b;
            split_bf16(vv[j], a, b);
            if (j < 8) { h0[j] = a; l0[j] = b; } else { h1[j - 8] = a; l1[j - 8] = b; }
            qv[j] = q8(vv[j], qs);
        }
        *(ushort8v*)(xhi + (size_t)t * 16) = h0;
        *(ushort8v*)(xhi + (size_t)t * 16 + 8) = h1;
        *(ushort8v*)(xlo + (size_t)t * 16) = l0;
        *(ushort8v*)(xlo + (size_t)t * 16 + 8) = l1;
        *(uchar16*)(xq + (size_t)t * 16) = qv;
        if ((t & 7) == 0) xsc[t >> 3] = m * (1.0f / 127.0f);
    } else {
        const int hb = blockIdx.x - 1883;
        const int base = hb * 4096;
        if (threadIdx.x < NBUCK) lhist[threadIdx.x] = 0;
        __syncthreads();
#pragma unroll
        for (int i = 0; i < 16; ++i) {
            int e = base + i * 256 + threadIdx.x;
            if (e < N_EDGES) atomicAdd(&lhist[dst[e] >> 8], 1);
        }
        __syncthreads();
        if (threadIdx.x < NBUCK) blkhist[hb * NBUCK + threadIdx.x] = lhist[threadIdx.x];
    }
}

// ---------------- bucket scan (1 block): blkhist -> bucketBase/bucketCur -----

__global__ void scan_sums_kernel(const int* __restrict__ blkhist,
                                 int* __restrict__ bucketBase, int* __restrict__ bucketCur,
                                 int* __restrict__ rowptr) {
    __shared__ int s[256];
    int tid = threadIdx.x;
    int v = 0;
    if (tid < NBUCK)
        for (int h = 0; h < NHIST; ++h) v += blkhist[h * NBUCK + tid];
    s[tid] = v;
    __syncthreads();
    for (int off = 1; off < 256; off <<= 1) {
        int t = (tid >= off) ? s[tid - off] : 0;
        __syncthreads();
        s[tid] += t;
        __syncthreads();
    }
    if (tid < NBUCK) {
        int b = s[tid] - v;
        bucketBase[tid] = b;
        bucketCur[tid] = b;
    }
    if (tid == 0) { bucketBase[NBUCK] = N_EDGES; rowptr[N_NODES] = N_EDGES; }
}

// ---------------- edge partition into 196 buckets (LDS-staged, coalesced) ----

__global__ __launch_bounds__(256) void partition_kernel(
    const int* __restrict__ src, const int* __restrict__ dst,
    int* __restrict__ bucketCur, unsigned int* __restrict__ ebuf, int E) {
    __shared__ int hist[NBUCK], binoff[NBUCK], bincur[NBUCK], runstart[NBUCK];
    __shared__ int scanbuf[256];
    __shared__ unsigned int sortbuf[2048];
    const int tid = threadIdx.x;
    const int base = blockIdx.x * 2048;
    if (tid < NBUCK) hist[tid] = 0;
    __syncthreads();
    int myb[8]; unsigned int myp[8];
#pragma unroll
    for (int i = 0; i < 8; ++i) {
        int e = base + i * 256 + tid;
        if (e < E) {
            int d = dst[e], s = src[e];
            myb[i] = d >> 8;
            myp[i] = ((unsigned)d << 16) | (unsigned)s;
            atomicAdd(&hist[myb[i]], 1);
        } else myb[i] = -1;
    }
    __syncthreads();
    int v = (tid < NBUCK) ? hist[tid] : 0;
    scanbuf[tid] = v;
    __syncthreads();
    for (int off = 1; off < 256; off <<= 1) {
        int t = (tid >= off) ? scanbuf[tid - off] : 0;
        __syncthreads();
        scanbuf[tid] += t;
        __syncthreads();
    }
    if (tid < NBUCK) {
        binoff[tid] = scanbuf[tid] - v;
        bincur[tid] = 0;
        runstart[tid] = atomicAdd(&bucketCur[tid], v);
    }
    __syncthreads();
#pragma unroll
    for (int i = 0; i < 8; ++i) {
        if (myb[i] >= 0) {
            int r = atomicAdd(&bincur[myb[i]], 1);
            sortbuf[binoff[myb[i]] + r] = myp[i];
        }
    }
    __syncthreads();
    int nloc = E - base; if (nloc > 2048) nloc = 2048;
#pragma unroll
    for (int i = 0; i < 8; ++i) {
        int idx = i * 256 + tid;
        if (idx < nloc) {
            unsigned int p = sortbuf[idx];
            int b = p >> 24;   // dst>>8
            ebuf[runstart[b] + (idx - binoff[b])] = p;
        }
    }
}

// ---------------- fine fill: per bucket, derive rowptr + scatter esrc ---------

__global__ __launch_bounds__(256) void fine_fill_kernel(
    const unsigned int* __restrict__ ebuf, const int* __restrict__ bucketBase,
    int* __restrict__ rowptr, unsigned short* __restrict__ esrc, int n) {
    __shared__ int cnt[256], scanbuf[256], cur[256];
    const int b = blockIdx.x, tid = threadIdx.x;
    const int nbase = b << 8;
    cnt[tid] = 0;
    __syncthreads();
    const int lo = bucketBase[b], hi = bucketBase[b + 1];
    for (int k = lo + tid; k < hi; k += 256)
        atomicAdd(&cnt[(ebuf[k] >> 16) & 255], 1);
    __syncthreads();
    int v = cnt[tid];
    scanbuf[tid] = v;
    __syncthreads();
    for (int off = 1; off < 256; off <<= 1) {
        int t = (tid >= off) ? scanbuf[tid - off] : 0;
        __syncthreads();
        scanbuf[tid] += t;
        __syncthreads();
    }
    int start = lo + scanbuf[tid] - v;   // exclusive
    if (nbase + tid < n) rowptr[nbase + tid] = start;
    cur[tid] = start;
    __syncthreads();
    for (int k = lo + tid; k < hi; k += 256) {
        unsigned int p = ebuf[k];
        int pos = atomicAdd(&cur[(p >> 16) & 255], 1);
        esrc[pos] = (unsigned short)(p & 0xFFFFu);
    }
}

// ---------------- mean aggregation (two-pass, L2-resident slice) -------------
// R9: TEMPORAL column slicing. R7 halved gather lines/edge for only -3us ->
// the gather is latency-bound, not line-count-bound: the 6.4MB int8 table
// exceeds the 4MiB per-XCD L2, so every access pays L3 latency (~500cy).
// Run the agg as TWO sequential passes over a 64-col slice (SLICE template
// arg): slice footprint = 3.2MB < 4MiB -> L2-resident on every XCD with no
// placement assumption (the R6 steering failure doesn't apply). 1 line/edge,
// 16 lanes x 4B. Per-column summation order identical to R7 (same a0/a1
// alternation) -> numerics bit-identical. Extra cost: 1 more launch + 3.2MB
// streamed esrc re-read per layer.

template <int SLICE>
__global__ __launch_bounds__(256, 8) void agg_kernel(
    const unsigned char* __restrict__ Hq, const float* __restrict__ Hsc,
    const int* __restrict__ rowptr, const unsigned short* __restrict__ esrc,
    unsigned short* __restrict__ Ahi, int n) {
    int g = (blockIdx.x * blockDim.x + threadIdx.x) >> 4;
    int l16 = threadIdx.x & 15;
    if (g >= n) return;
    int beg = rowptr[g], end = rowptr[g + 1];
    const unsigned char* __restrict__ Hb = Hq + SLICE * 64 + l16 * 4;
    float a0[4] = {0,0,0,0}, a1[4] = {0,0,0,0};
    float sacc = 0.f;
    int k = beg;
    // 6-deep main loop: 6 independent 4B gathers (+6 scale hits) in flight
    for (; k + 6 <= end; k += 6) {
        int e0 = esrc[k],     e1 = esrc[k + 1], e2 = esrc[k + 2];
        int e3 = esrc[k + 3], e4 = esrc[k + 4], e5 = esrc[k + 5];
        unsigned w0 = *(const unsigned*)(Hb + (size_t)e0 * 128);
        unsigned w1 = *(const unsigned*)(Hb + (size_t)e1 * 128);
        unsigned w2 = *(const unsigned*)(Hb + (size_t)e2 * 128);
        unsigned w3 = *(const unsigned*)(Hb + (size_t)e3 * 128);
        unsigned w4 = *(const unsigned*)(Hb + (size_t)e4 * 128);
        unsigned w5 = *(const unsigned*)(Hb + (size_t)e5 * 128);
        float s0 = Hsc[e0], s1 = Hsc[e1], s2 = Hsc[e2];
        float s3 = Hsc[e3], s4 = Hsc[e4], s5 = Hsc[e5];
        acc4(a0, w0, s0); acc4(a1, w1, s1); acc4(a0, w2, s2);
        acc4(a1, w3, s3); acc4(a0, w4, s4); acc4(a1, w5, s5);
        sacc += s0 + s1 + s2 + s3 + s4 + s5;
    }
    // pair drain
    for (; k + 2 <= end; k += 2) {
        int e0 = esrc[k], e1 = esrc[k + 1];
        unsigned w0 = *(const unsigned*)(Hb + (size_t)e0 * 128);
        unsigned w1 = *(const unsigned*)(Hb + (size_t)e1 * 128);
        float s0 = Hsc[e0], s1 = Hsc[e1];
        acc4(a0, w0, s0); acc4(a1, w1, s1);
        sacc += s0 + s1;
    }
    if (k < end) {
        int e0 = esrc[k];
        unsigned w0 = *(const unsigned*)(Hb + (size_t)e0 * 128);
        float s0 = Hsc[e0];
        acc4(a0, w0, s0);
        sacc += s0;
    }
    float inv = (end > beg) ? 1.0f / (float)(end - beg) : 0.0f;
    ushort4v mh;
#pragma unroll
    for (int j = 0; j < 4; ++j)
        mh[j] = f2bf((a0[j] + a1[j] - 128.0f * sacc) * inv);
    *(ushort4v*)(Ahi + (size_t)g * 128 + SLICE * 64 + l16 * 4) = mh;
}

// ---------------- dual GEMM via MFMA (R7-exact, BM=32) -----------------------
// out = A1@W1 + A2@W2 + b. agg: 2 MFMAs (hi*bhi+hi*blo); self: 3 MFMAs.
// BM=32, 256 thr = 4 waves, (256,4). R8's BM=64 regressed (+8us) -> reverted.
// SPLIT_OUT epilogue also emits the int8+scale plane for the next gather.

template <int DOUT, bool RELU, bool SPLIT_OUT>
__global__ __launch_bounds__(256, 4) void gemm_planes(
    const unsigned short* __restrict__ A1hi,
    const unsigned short* __restrict__ A2hi, const unsigned short* __restrict__ A2lo,
    const unsigned short* __restrict__ B1p, const unsigned short* __restrict__ B2p,
    const float* __restrict__ bias, float* __restrict__ outf,
    unsigned short* __restrict__ outhi, unsigned short* __restrict__ outlo,
    unsigned char* __restrict__ outq, float* __restrict__ outsc, int M) {
    constexpr int K = 128, BM = 32, KS = 4, CT = DOUT / 16, CPW = CT / 4;
    constexpr int PITCH = K + 8;
    constexpr int HALF = CT * KS * 512;
    __shared__ unsigned short As[3][BM * PITCH];  // [agg-hi, self-hi, self-lo]
    __shared__ float wmax[BM][4];

    const int tid = threadIdx.x;
    const int r0 = blockIdx.x * BM;

    const unsigned short* __restrict__ srcs[3] = {A1hi, A2hi, A2lo};
#pragma unroll
    for (int s = 0; s < 3; ++s) {
#pragma unroll
        for (int c = 0; c < 2; ++c) {
            int chunk = tid + c * 256;
            int row = chunk >> 4;
            int c8 = (chunk & 15) * 8;
            int grow = r0 + row; if (grow >= M) grow = M - 1;
            *(ushort8v*)(&As[s][row * PITCH + c8]) =
                *(const ushort8v*)(srcs[s] + (size_t)grow * K + c8);
        }
    }
    __syncthreads();

    const int wave = tid >> 6, lane = tid & 63;
    const int rl = lane & 15, quad = lane >> 4;

    f32x4 acc[2][CPW];
#pragma unroll
    for (int c = 0; c < CPW; ++c) {
        float bv = bias[(wave * CPW + c) * 16 + rl];
        acc[0][c] = (f32x4){bv, bv, bv, bv};
        acc[1][c] = acc[0][c];
    }

#pragma unroll
    for (int ks = 0; ks < KS; ++ks) {
        short8 a_ag[2], a_sh[2][2];
#pragma unroll
        for (int rt = 0; rt < 2; ++rt) {
            int off = (rt * 16 + rl) * PITCH + ks * 32 + quad * 8;
            a_ag[rt]    = *(const short8*)(&As[0][off]);
            a_sh[rt][0] = *(const short8*)(&As[1][off]);
            a_sh[rt][1] = *(const short8*)(&As[2][off]);
        }
        short8 b1[CPW][2], b2[CPW][2];
#pragma unroll
        for (int c = 0; c < CPW; ++c) {
            size_t boff = (((wave * CPW + c) * KS + ks) * 64 + lane) * 8;
#pragma unroll
            for (int p = 0; p < 2; ++p) {
                b1[c][p] = *(const short8*)(B1p + p * HALF + boff);
                b2[c][p] = *(const short8*)(B2p + p * HALF + boff);
            }
        }
#pragma unroll
        for (int rt = 0; rt < 2; ++rt)
#pragma unroll
            for (int c = 0; c < CPW; ++c) {
                acc[rt][c] = __builtin_amdgcn_mfma_f32_16x16x32_bf16(a_ag[rt],    b1[c][0], acc[rt][c], 0, 0, 0);
                acc[rt][c] = __builtin_amdgcn_mfma_f32_16x16x32_bf16(a_ag[rt],    b1[c][1], acc[rt][c], 0, 0, 0);
                acc[rt][c] = __builtin_amdgcn_mfma_f32_16x16x32_bf16(a_sh[rt][0], b2[c][0], acc[rt][c], 0, 0, 0);
                acc[rt][c] = __builtin_amdgcn_mfma_f32_16x16x32_bf16(a_sh[rt][0], b2[c][1], acc[rt][c], 0, 0, 0);
                acc[rt][c] = __builtin_amdgcn_mfma_f32_16x16x32_bf16(a_sh[rt][1], b2[c][0], acc[rt][c], 0, 0, 0);
            }
    }

    // ---- apply ReLU once, in-register ----
    if (RELU) {
#pragma unroll
        for (int rt = 0; rt < 2; ++rt)
#pragma unroll
            for (int c = 0; c < CPW; ++c)
#pragma unroll
                for (int r = 0; r < 4; ++r)
                    acc[rt][c][r] = fmaxf(acc[rt][c][r], 0.f);
    }

    float qsc[2][4];
    if constexpr (SPLIT_OUT) {
        // per-lane rowmax over its CPW cols, then 16-lane shfl, then cross-wave LDS
        float lm[2][4];
#pragma unroll
        for (int rt = 0; rt < 2; ++rt)
#pragma unroll
            for (int r = 0; r < 4; ++r) {
                float m = fabsf(acc[rt][0][r]);
#pragma unroll
                for (int c = 1; c < CPW; ++c) m = fmaxf(m, fabsf(acc[rt][c][r]));
                lm[rt][r] = m;
            }
#pragma unroll
        for (int off = 1; off < 16; off <<= 1)
#pragma unroll
            for (int rt = 0; rt < 2; ++rt)
#pragma unroll
                for (int r = 0; r < 4; ++r)
                    lm[rt][r] = fmaxf(lm[rt][r], __shfl_xor(lm[rt][r], off));
        if (rl == 0) {
#pragma unroll
            for (int rt = 0; rt < 2; ++rt)
#pragma unroll
                for (int r = 0; r < 4; ++r)
                    wmax[rt * 16 + quad * 4 + r][wave] = lm[rt][r];
        }
        __syncthreads();
#pragma unroll
        for (int rt = 0; rt < 2; ++rt)
#pragma unroll
            for (int r = 0; r < 4; ++r) {
                int row = rt * 16 + quad * 4 + r;
                float rm = fmaxf(fmaxf(wmax[row][0], wmax[row][1]),
                                 fmaxf(wmax[row][2], wmax[row][3]));
                qsc[rt][r] = rm > 0.f ? 127.0f / rm : 0.0f;
                if (wave == 0 && rl == 0) {
                    int rr = r0 + row;
                    if (rr < M) outsc[rr] = rm * (1.0f / 127.0f);
                }
            }
    }

    // ---- epilogue: C/D layout col=lane&15, row=quad*4+reg ----
#pragma unroll
    for (int rt = 0; rt < 2; ++rt)
#pragma unroll
        for (int c = 0; c < CPW; ++c) {
            int col = (wave * CPW + c) * 16 + rl;
            int rowb = r0 + rt * 16 + quad * 4;
#pragma unroll
            for (int r = 0; r < 4; ++r) {
                int rr = rowb + r;
                if (rr < M) {
                    float vv = acc[rt][c][r];
                    if (SPLIT_OUT) {
                        unsigned short h, l;
                        split_bf16(vv, h, l);
                        outhi[(size_t)rr * DOUT + col] = h;
                        outlo[(size_t)rr * DOUT + col] = l;
                        outq[(size_t)rr * DOUT + col] = q8(vv, qsc[rt][r]);
                    } else {
                        outf[(size_t)rr * DOUT + col] = vv;
                    }
                }
            }
        }
}

// ---------------- launch ----------------

extern "C" void kernel_launch(void* const* d_in, const int* in_sizes, int n_in,
                              void* d_out, int out_size, void* d_ws, size_t ws_size,
                              hipStream_t stream) {
    const float* x   = (const float*)d_in[0];
    const int* eidx  = (const int*)d_in[1];
    const int* src   = eidx;             // edge_index[0]
    const int* dst   = eidx + N_EDGES;   // edge_index[1]
    const float* Wl0 = (const float*)d_in[2];
    const float* b0  = (const float*)d_in[3];
    const float* Wr0 = (const float*)d_in[4];
    const float* Wl1 = (const float*)d_in[5];
    const float* b1  = (const float*)d_in[6];
    const float* Wr1 = (const float*)d_in[7];
    const float* Wl2 = (const float*)d_in[8];
    const float* b2  = (const float*)d_in[9];
    const float* Wr2 = (const float*)d_in[10];
    float* outp = (float*)d_out;

    // workspace (~48 MB, R0-verified layout + int8 plane)
    unsigned short* xhi  = (unsigned short*)d_ws;           // N*128 each
    unsigned short* xlo  = xhi + (size_t)N_NODES * 128;
    unsigned short* aghi = xlo + (size_t)N_NODES * 128;
    unsigned int* ebuf = (unsigned int*)aghi;               // ALIAS: consumed before agg writes
    int* rowptr    = (int*)(aghi + (size_t)N_NODES * 128);  // 50016
    int* blkhist   = rowptr + 50016;                        // 196*196 = 38416
    int* bucketBase= blkhist + 38416;                       // 256 (197 used)
    int* bucketCur = bucketBase + 256;                      // 256
    unsigned short* esrc  = (unsigned short*)(bucketCur + 256); // E ushort = 1.6MB
    unsigned short* packw = esrc + N_EDGES;                 // 163840 bf16 (16B-aligned)
    unsigned short* Wl0p = packw;
    unsigned short* Wr0p = packw + 32768;
    unsigned short* Wl1p = packw + 65536;
    unsigned short* Wr1p = packw + 98304;
    unsigned short* Wl2p = packw + 131072;
    unsigned short* Wr2p = packw + 147456;
    unsigned char* xq = (unsigned char*)(packw + 163840);   // N*128 int8 = 6.4MB (16B-aligned)
    float* xsc = (float*)(xq + (size_t)N_NODES * 128);      // N f32 = 200KB

    // --- prep (pack W + split/quantize x + per-block bucket hist) ---
    prep_kernel<<<2079, 256, 0, stream>>>(Wl0, Wr0, Wl1, Wr1, Wl2, Wr2, packw,
                                          x, xhi, xlo, xq, xsc, dst, blkhist);
    // --- bucket scan (1 block) -> bucketBase/bucketCur, rowptr[N]=E ---
    scan_sums_kernel<<<1, 256, 0, stream>>>(blkhist, bucketBase, bucketCur, rowptr);
    // --- partition edges into buckets (coalesced), then per-bucket CSR ---
    partition_kernel<<<(N_EDGES + 2047) / 2048, 256, 0, stream>>>(src, dst, bucketCur, ebuf, N_EDGES);
    fine_fill_kernel<<<NBUCK, 256, 0, stream>>>(ebuf, bucketBase, rowptr, esrc, N_NODES);

    const int aggGrid = (N_NODES * 16 + 255) / 256;   // 3125
    const int gemmGrid = (N_NODES + 31) / 32;         // 1563

    // layer 0: x -> x (in place, ReLU); epilogue re-quantizes int8 plane in place
    agg_kernel<0><<<aggGrid, 256, 0, stream>>>(xq, xsc, rowptr, esrc, aghi, N_NODES);
    agg_kernel<1><<<aggGrid, 256, 0, stream>>>(xq, xsc, rowptr, esrc, aghi, N_NODES);
    gemm_planes<128, true, true><<<gemmGrid, 256, 0, stream>>>(
        aghi, xhi, xlo, Wl0p, Wr0p, b0, nullptr, xhi, xlo, xq, xsc, N_NODES);
    // layer 1: x -> x (in place, ReLU)
    agg_kernel<0><<<aggGrid, 256, 0, stream>>>(xq, xsc, rowptr, esrc, aghi, N_NODES);
    agg_kernel<1><<<aggGrid, 256, 0, stream>>>(xq, xsc, rowptr, esrc, aghi, N_NODES);
    gemm_planes<128, true, true><<<gemmGrid, 256, 0, stream>>>(
        aghi, xhi, xlo, Wl1p, Wr1p, b1, nullptr, xhi, xlo, xq, xsc, N_NODES);
    // layer 2: x -> out (f32, no ReLU, DOUT=64)
    agg_kernel<0><<<aggGrid, 256, 0, stream>>>(xq, xsc, rowptr, esrc, aghi, N_NODES);
    agg_kernel<1><<<aggGrid, 256, 0, stream>>>(xq, xsc, rowptr, esrc, aghi, N_NODES);
    gemm_planes<64, false, false><<<gemmGrid, 256, 0, stream>>>(
        aghi, xhi, xlo, Wl2p, Wr2p, b2, outp, nullptr, nullptr, nullptr, nullptr, N_NODES);
}

// Round 10
// 241.164 us; speedup vs baseline: 1.2146x; 1.2146x over previous
//
#include <hip/hip_runtime.h>

#define N_NODES 50000
#define N_EDGES 800000
#define NBUCK 196       // dst>>8 -> 0..195
#define BCAP 8192       // fixed ebuf region per bucket (mean 4096, sd ~64)

typedef __attribute__((ext_vector_type(8))) short short8;
typedef __attribute__((ext_vector_type(4))) float f32x4;
typedef __attribute__((ext_vector_type(8))) unsigned short ushort8v;
typedef __attribute__((ext_vector_type(16))) unsigned char uchar16;

// ---------------- helpers ----------------

__device__ inline void split_bf16(float f, unsigned short& hi, unsigned short& lo) {
    union { float f; unsigned u; } a; a.f = f;
    unsigned r = (a.u + 0x7fffu + ((a.u >> 16) & 1u)) >> 16;  // RNE to bf16
    hi = (unsigned short)r;
    union { unsigned u; float f; } b; b.u = r << 16;
    union { float f; unsigned u; } c; c.f = f - b.f;
    unsigned r2 = (c.u + 0x7fffu + ((c.u >> 16) & 1u)) >> 16;
    lo = (unsigned short)r2;
}

__device__ inline unsigned short f2bf(float f) {
    union { float f; unsigned u; } a; a.f = f;
    return (unsigned short)((a.u + 0x7fffu + ((a.u >> 16) & 1u)) >> 16);
}

__device__ inline float bf2f(unsigned short u) {
    union { unsigned u; float f; } a; a.u = (unsigned)u << 16; return a.f;
}

__device__ inline unsigned char q8(float v, float qs) {
    int qi = (int)rintf(v * qs);
    qi = qi > 127 ? 127 : (qi < -127 ? -127 : qi);
    return (unsigned char)(qi + 128);
}

// accumulate 8 biased-u8 values (uint2) scaled by s into a[0..7]
__device__ inline void acc8(float* a, uint2 w, float s) {
#pragma unroll
    for (int j = 0; j < 4; ++j) {
        a[j]     += (float)((w.x >> (8 * j)) & 255u) * s;
        a[j + 4] += (float)((w.y >> (8 * j)) & 255u) * s;
    }
}

// ---------------- prep: pack(W) + split/quantize(x) + zero bucketCur ---------
// R10: histogram + scan phases DELETED (fixed bucket regions make the global
// prefix-scan unnecessary). Block 1883 zeroes bucketCur.

__global__ void prep_kernel(const float* __restrict__ W0, const float* __restrict__ W1,
                            const float* __restrict__ W2, const float* __restrict__ W3,
                            const float* __restrict__ W4, const float* __restrict__ W5,
                            unsigned short* __restrict__ wout,
                            const float* __restrict__ x, unsigned short* __restrict__ xhi,
                            unsigned short* __restrict__ xlo,
                            unsigned char* __restrict__ xq, float* __restrict__ xsc,
                            int* __restrict__ bucketCur) {
    if (blockIdx.x < 320) {
        int t = blockIdx.x * 256 + threadIdx.x;  // 0..81919
        const float* W; int D, local, half; size_t base;
        if (t < 65536) {
            int mat = t >> 14; local = t & 16383; D = 128; half = 16384;
            base = (size_t)mat * 32768;
            W = mat == 0 ? W0 : mat == 1 ? W1 : mat == 2 ? W2 : W3;
        } else {
            int m = (t - 65536) >> 13; local = (t - 65536) & 8191; D = 64; half = 8192;
            base = 131072 + (size_t)m * 16384;
            W = m == 0 ? W4 : W5;
        }
        int j = local & 7, lane = (local >> 3) & 63, ks = (local >> 9) & 3, ct = local >> 11;
        int k = ks * 32 + ((lane >> 4) << 3) + j;
        int n = (ct << 4) + (lane & 15);
        unsigned short hi, lo;
        split_bf16(W[k * D + n], hi, lo);
        wout[base + local] = hi;
        wout[base + half + local] = lo;
    } else if (blockIdx.x < 1883) {
        int t = (blockIdx.x - 320) * 256 + threadIdx.x;  // one 16-float chunk/thread
        if (t >= N_NODES * 8) return;                    // 50000*128/16 = 400000
        const float* p = x + (size_t)t * 16;
        float4 v0 = *(const float4*)(p);
        float4 v1 = *(const float4*)(p + 4);
        float4 v2 = *(const float4*)(p + 8);
        float4 v3 = *(const float4*)(p + 12);
        float vv[16] = {v0.x, v0.y, v0.z, v0.w, v1.x, v1.y, v1.z, v1.w,
                        v2.x, v2.y, v2.z, v2.w, v3.x, v3.y, v3.z, v3.w};
        // rowmax over 128 floats: 8 consecutive threads share a row (aligned)
        float m = 0.f;
#pragma unroll
        for (int j = 0; j < 16; ++j) m = fmaxf(m, fabsf(vv[j]));
        m = fmaxf(m, __shfl_xor(m, 1));
        m = fmaxf(m, __shfl_xor(m, 2));
        m = fmaxf(m, __shfl_xor(m, 4));
        float qs = m > 0.f ? 127.0f / m : 0.0f;
        uchar16 qv;
        ushort8v h0, l0, h1, l1;
#pragma unroll
        for (int j = 0; j < 16; ++j) {
            unsigned short a, b;
            split_bf16(vv[j], a, b);
            if (j < 8) { h0[j] = a; l0[j] = b; } else { h1[j - 8] = a; l1[j - 8] = b; }
            qv[j] = q8(vv[j], qs);
        }
        *(ushort8v*)(xhi + (size_t)t * 16) = h0;
        *(ushort8v*)(xhi + (size_t)t * 16 + 8) = h1;
        *(ushort8v*)(xlo + (size_t)t * 16) = l0;
        *(ushort8v*)(xlo + (size_t)t * 16 + 8) = l1;
        *(uchar16*)(xq + (size_t)t * 16) = qv;
        if ((t & 7) == 0) xsc[t >> 3] = m * (1.0f / 127.0f);
    } else {
        if (threadIdx.x < 256) bucketCur[threadIdx.x] = 0;
    }
}

// ---------------- edge partition into fixed bucket regions ------------------
// R10: region b = [b*BCAP, b*BCAP + cnt). No scan needed: runstart =
// b*BCAP + atomicAdd(bucketCur[b], v). LDS stage-sort unchanged (coalesced).

__global__ __launch_bounds__(256) void partition_kernel(
    const int* __restrict__ src, const int* __restrict__ dst,
    int* __restrict__ bucketCur, unsigned int* __restrict__ ebuf, int E) {
    __shared__ int hist[NBUCK], binoff[NBUCK], bincur[NBUCK], runstart[NBUCK];
    __shared__ int scanbuf[256];
    __shared__ unsigned int sortbuf[2048];
    const int tid = threadIdx.x;
    const int base = blockIdx.x * 2048;
    if (tid < NBUCK) hist[tid] = 0;
    __syncthreads();
    int myb[8]; unsigned int myp[8];
#pragma unroll
    for (int i = 0; i < 8; ++i) {
        int e = base + i * 256 + tid;
        if (e < E) {
            int d = dst[e], s = src[e];
            myb[i] = d >> 8;
            myp[i] = ((unsigned)d << 16) | (unsigned)s;
            atomicAdd(&hist[myb[i]], 1);
        } else myb[i] = -1;
    }
    __syncthreads();
    int v = (tid < NBUCK) ? hist[tid] : 0;
    scanbuf[tid] = v;
    __syncthreads();
    for (int off = 1; off < 256; off <<= 1) {
        int t = (tid >= off) ? scanbuf[tid - off] : 0;
        __syncthreads();
        scanbuf[tid] += t;
        __syncthreads();
    }
    if (tid < NBUCK) {
        binoff[tid] = scanbuf[tid] - v;
        bincur[tid] = 0;
        runstart[tid] = tid * BCAP + atomicAdd(&bucketCur[tid], v);
    }
    __syncthreads();
#pragma unroll
    for (int i = 0; i < 8; ++i) {
        if (myb[i] >= 0) {
            int r = atomicAdd(&bincur[myb[i]], 1);
            sortbuf[binoff[myb[i]] + r] = myp[i];
        }
    }
    __syncthreads();
    int nloc = E - base; if (nloc > 2048) nloc = 2048;
#pragma unroll
    for (int i = 0; i < 8; ++i) {
        int idx = i * 256 + tid;
        if (idx < nloc) {
            unsigned int p = sortbuf[idx];
            int b = p >> 24;   // dst>>8
            ebuf[runstart[b] + (idx - binoff[b])] = p;
        }
    }
}

// ---------------- fine fill: per bucket -> rowbeg/rowend + esrc --------------
// R10: emits explicit rowbeg/rowend (CSR contiguity not required with fixed
// bucket regions). esrc positions are region-coordinates (< NBUCK*BCAP).

__global__ __launch_bounds__(256) void fine_fill_kernel(
    const unsigned int* __restrict__ ebuf, const int* __restrict__ bucketCur,
    int* __restrict__ rowbeg, int* __restrict__ rowend,
    unsigned short* __restrict__ esrc, int n) {
    __shared__ int cnt[256], scanbuf[256], cur[256];
    const int b = blockIdx.x, tid = threadIdx.x;
    const int nbase = b << 8;
    cnt[tid] = 0;
    __syncthreads();
    const int lo = b * BCAP, hi = lo + bucketCur[b];
    for (int k = lo + tid; k < hi; k += 256)
        atomicAdd(&cnt[(ebuf[k] >> 16) & 255], 1);
    __syncthreads();
    int v = cnt[tid];
    scanbuf[tid] = v;
    __syncthreads();
    for (int off = 1; off < 256; off <<= 1) {
        int t = (tid >= off) ? scanbuf[tid - off] : 0;
        __syncthreads();
        scanbuf[tid] += t;
        __syncthreads();
    }
    int start = lo + scanbuf[tid] - v;   // exclusive
    if (nbase + tid < n) { rowbeg[nbase + tid] = start; rowend[nbase + tid] = start + v; }
    cur[tid] = start;
    __syncthreads();
    for (int k = lo + tid; k < hi; k += 256) {
        unsigned int p = ebuf[k];
        int pos = atomicAdd(&cur[(p >> 16) & 255], 1);
        esrc[pos] = (unsigned short)(p & 0xFFFFu);
    }
}

// ---------------- fused SAGE layer: int8 gather-mean + dual MFMA GEMM --------
// R10: R1's proven fused skeleton (3-plane LDS staging, ping-pong buffers) +
// R7's int8+scale gather in Phase B + R7's quantizing epilogue. 6 launches
// total (launch overhead ~8us/kernel was the R9 lesson). (256,4): VGPR cap
// 128 >> ~90 live -> no spill regime (R3 lesson).
// Phase A: stage this block's 32 self rows (hi+lo) into As[1],As[2].
// Phase B: each 16-lane group mean-aggregates 2 rows (int8+scale, 6-deep,
//   identical loop body/summation order to R7's agg_kernel) into As[0].
// Phase C: dual GEMM (R7-exact) + quantizing epilogue.

template <int DOUT, bool RELU, bool SPLIT_OUT>
__global__ __launch_bounds__(256, 4) void sage_layer(
    const unsigned char* __restrict__ Hq, const float* __restrict__ Hsc,
    const unsigned short* __restrict__ Hhi, const unsigned short* __restrict__ Hlo,
    const int* __restrict__ rowbeg, const int* __restrict__ rowend,
    const unsigned short* __restrict__ esrc,
    const unsigned short* __restrict__ B1p, const unsigned short* __restrict__ B2p,
    const float* __restrict__ bias, float* __restrict__ outf,
    unsigned short* __restrict__ outhi, unsigned short* __restrict__ outlo,
    unsigned char* __restrict__ outq, float* __restrict__ outsc, int M) {
    constexpr int K = 128, BM = 32, KS = 4, CT = DOUT / 16, CPW = CT / 4;
    constexpr int PITCH = K + 8;
    constexpr int HALF = CT * KS * 512;
    __shared__ unsigned short As[3][BM * PITCH];  // [agg-hi, self-hi, self-lo]
    __shared__ float wmax[BM][4];

    const int tid = threadIdx.x;
    const int r0 = blockIdx.x * BM;

    // ---- Phase A: stage self hi/lo rows (coalesced) ----
    const unsigned short* __restrict__ srcs[2] = {Hhi, Hlo};
#pragma unroll
    for (int s = 0; s < 2; ++s) {
#pragma unroll
        for (int c = 0; c < 2; ++c) {
            int chunk = tid + c * 256;
            int row = chunk >> 4;
            int c8 = (chunk & 15) * 8;
            int grow = r0 + row; if (grow >= M) grow = M - 1;
            *(ushort8v*)(&As[s + 1][row * PITCH + c8]) =
                *(const ushort8v*)(srcs[s] + (size_t)grow * K + c8);
        }
    }

    // ---- Phase B: int8 gather-mean into As[0] (R7 loop body, 2 rows/group) --
    {
        const int g16 = tid >> 4, l16 = tid & 15;
        const unsigned char* __restrict__ Hb = Hq + l16 * 8;
#pragma unroll
        for (int nn = 0; nn < 2; ++nn) {
            int row = g16 * 2 + nn;
            int node = r0 + row; if (node >= M) node = M - 1;  // pad: harmless dup
            int beg = rowbeg[node], end = rowend[node];
            float a0[8] = {0,0,0,0,0,0,0,0}, a1[8] = {0,0,0,0,0,0,0,0};
            float sacc = 0.f;
            int k = beg;
            for (; k + 6 <= end; k += 6) {
                int e0 = esrc[k],     e1 = esrc[k + 1], e2 = esrc[k + 2];
                int e3 = esrc[k + 3], e4 = esrc[k + 4], e5 = esrc[k + 5];
                uint2 w0 = *(const uint2*)(Hb + (size_t)e0 * 128);
                uint2 w1 = *(const uint2*)(Hb + (size_t)e1 * 128);
                uint2 w2 = *(const uint2*)(Hb + (size_t)e2 * 128);
                uint2 w3 = *(const uint2*)(Hb + (size_t)e3 * 128);
                uint2 w4 = *(const uint2*)(Hb + (size_t)e4 * 128);
                uint2 w5 = *(const uint2*)(Hb + (size_t)e5 * 128);
                float s0 = Hsc[e0], s1 = Hsc[e1], s2 = Hsc[e2];
                float s3 = Hsc[e3], s4 = Hsc[e4], s5 = Hsc[e5];
                acc8(a0, w0, s0); acc8(a1, w1, s1); acc8(a0, w2, s2);
                acc8(a1, w3, s3); acc8(a0, w4, s4); acc8(a1, w5, s5);
                sacc += s0 + s1 + s2 + s3 + s4 + s5;
            }
            for (; k + 2 <= end; k += 2) {
                int e0 = esrc[k], e1 = esrc[k + 1];
                uint2 w0 = *(const uint2*)(Hb + (size_t)e0 * 128);
                uint2 w1 = *(const uint2*)(Hb + (size_t)e1 * 128);
                float s0 = Hsc[e0], s1 = Hsc[e1];
                acc8(a0, w0, s0); acc8(a1, w1, s1);
                sacc += s0 + s1;
            }
            if (k < end) {
                int e0 = esrc[k];
                uint2 w0 = *(const uint2*)(Hb + (size_t)e0 * 128);
                float s0 = Hsc[e0];
                acc8(a0, w0, s0);
                sacc += s0;
            }
            float inv = (end > beg) ? 1.0f / (float)(end - beg) : 0.0f;
            ushort8v mh;
#pragma unroll
            for (int j = 0; j < 8; ++j)
                mh[j] = f2bf((a0[j] + a1[j] - 128.0f * sacc) * inv);
            *(ushort8v*)(&As[0][row * PITCH + l16 * 8]) = mh;
        }
    }
    __syncthreads();

    // ---- Phase C: dual GEMM via MFMA (R7-exact) ----
    const int wave = tid >> 6, lane = tid & 63;
    const int rl = lane & 15, quad = lane >> 4;

    f32x4 acc[2][CPW];
#pragma unroll
    for (int c = 0; c < CPW; ++c) {
        float bv = bias[(wave * CPW + c) * 16 + rl];
        acc[0][c] = (f32x4){bv, bv, bv, bv};
        acc[1][c] = acc[0][c];
    }

#pragma unroll
    for (int ks = 0; ks < KS; ++ks) {
        short8 a_ag[2], a_sh[2][2];
#pragma unroll
        for (int rt = 0; rt < 2; ++rt) {
            int off = (rt * 16 + rl) * PITCH + ks * 32 + quad * 8;
            a_ag[rt]    = *(const short8*)(&As[0][off]);
            a_sh[rt][0] = *(const short8*)(&As[1][off]);
            a_sh[rt][1] = *(const short8*)(&As[2][off]);
        }
        short8 b1[CPW][2], b2[CPW][2];
#pragma unroll
        for (int c = 0; c < CPW; ++c) {
            size_t boff = (((wave * CPW + c) * KS + ks) * 64 + lane) * 8;
#pragma unroll
            for (int p = 0; p < 2; ++p) {
                b1[c][p] = *(const short8*)(B1p + p * HALF + boff);
                b2[c][p] = *(const short8*)(B2p + p * HALF + boff);
            }
        }
#pragma unroll
        for (int rt = 0; rt < 2; ++rt)
#pragma unroll
            for (int c = 0; c < CPW; ++c) {
                acc[rt][c] = __builtin_amdgcn_mfma_f32_16x16x32_bf16(a_ag[rt],    b1[c][0], acc[rt][c], 0, 0, 0);
                acc[rt][c] = __builtin_amdgcn_mfma_f32_16x16x32_bf16(a_ag[rt],    b1[c][1], acc[rt][c], 0, 0, 0);
                acc[rt][c] = __builtin_amdgcn_mfma_f32_16x16x32_bf16(a_sh[rt][0], b2[c][0], acc[rt][c], 0, 0, 0);
                acc[rt][c] = __builtin_amdgcn_mfma_f32_16x16x32_bf16(a_sh[rt][0], b2[c][1], acc[rt][c], 0, 0, 0);
                acc[rt][c] = __builtin_amdgcn_mfma_f32_16x16x32_bf16(a_sh[rt][1], b2[c][0], acc[rt][c], 0, 0, 0);
            }
    }

    // ---- apply ReLU once, in-register ----
    if (RELU) {
#pragma unroll
        for (int rt = 0; rt < 2; ++rt)
#pragma unroll
            for (int c = 0; c < CPW; ++c)
#pragma unroll
                for (int r = 0; r < 4; ++r)
                    acc[rt][c][r] = fmaxf(acc[rt][c][r], 0.f);
    }

    float qsc[2][4];
    if constexpr (SPLIT_OUT) {
        float lm[2][4];
#pragma unroll
        for (int rt = 0; rt < 2; ++rt)
#pragma unroll
            for (int r = 0; r < 4; ++r) {
                float m = fabsf(acc[rt][0][r]);
#pragma unroll
                for (int c = 1; c < CPW; ++c) m = fmaxf(m, fabsf(acc[rt][c][r]));
                lm[rt][r] = m;
            }
#pragma unroll
        for (int off = 1; off < 16; off <<= 1)
#pragma unroll
            for (int rt = 0; rt < 2; ++rt)
#pragma unroll
                for (int r = 0; r < 4; ++r)
                    lm[rt][r] = fmaxf(lm[rt][r], __shfl_xor(lm[rt][r], off));
        if (rl == 0) {
#pragma unroll
            for (int rt = 0; rt < 2; ++rt)
#pragma unroll
                for (int r = 0; r < 4; ++r)
                    wmax[rt * 16 + quad * 4 + r][wave] = lm[rt][r];
        }
        __syncthreads();
#pragma unroll
        for (int rt = 0; rt < 2; ++rt)
#pragma unroll
            for (int r = 0; r < 4; ++r) {
                int row = rt * 16 + quad * 4 + r;
                float rm = fmaxf(fmaxf(wmax[row][0], wmax[row][1]),
                                 fmaxf(wmax[row][2], wmax[row][3]));
                qsc[rt][r] = rm > 0.f ? 127.0f / rm : 0.0f;
                if (wave == 0 && rl == 0) {
                    int rr = r0 + row;
                    if (rr < M) outsc[rr] = rm * (1.0f / 127.0f);
                }
            }
    }

    // ---- epilogue: C/D layout col=lane&15, row=quad*4+reg ----
#pragma unroll
    for (int rt = 0; rt < 2; ++rt)
#pragma unroll
        for (int c = 0; c < CPW; ++c) {
            int col = (wave * CPW + c) * 16 + rl;
            int rowb = r0 + rt * 16 + quad * 4;
#pragma unroll
            for (int r = 0; r < 4; ++r) {
                int rr = rowb + r;
                if (rr < M) {
                    float vv = acc[rt][c][r];
                    if (SPLIT_OUT) {
                        unsigned short h, l;
                        split_bf16(vv, h, l);
                        outhi[(size_t)rr * DOUT + col] = h;
                        outlo[(size_t)rr * DOUT + col] = l;
                        outq[(size_t)rr * DOUT + col] = q8(vv, qsc[rt][r]);
                    } else {
                        outf[(size_t)rr * DOUT + col] = vv;
                    }
                }
            }
        }
}

// ---------------- launch ----------------

extern "C" void kernel_launch(void* const* d_in, const int* in_sizes, int n_in,
                              void* d_out, int out_size, void* d_ws, size_t ws_size,
                              hipStream_t stream) {
    const float* x   = (const float*)d_in[0];
    const int* eidx  = (const int*)d_in[1];
    const int* src   = eidx;             // edge_index[0]
    const int* dst   = eidx + N_EDGES;   // edge_index[1]
    const float* Wl0 = (const float*)d_in[2];
    const float* b0  = (const float*)d_in[3];
    const float* Wr0 = (const float*)d_in[4];
    const float* Wl1 = (const float*)d_in[5];
    const float* b1  = (const float*)d_in[6];
    const float* Wr1 = (const float*)d_in[7];
    const float* Wl2 = (const float*)d_in[8];
    const float* b2  = (const float*)d_in[9];
    const float* Wr2 = (const float*)d_in[10];
    float* outp = (float*)d_out;

    // workspace (~70 MB): ping-pong plane sets + fixed-region CSR scratch
    unsigned short* xhi  = (unsigned short*)d_ws;             // N*128 u16 each
    unsigned short* xlo  = xhi + (size_t)N_NODES * 128;
    unsigned short* yhi  = xlo + (size_t)N_NODES * 128;
    unsigned short* ylo  = yhi + (size_t)N_NODES * 128;
    unsigned int* ebuf = (unsigned int*)yhi;                  // ALIAS: NBUCK*BCAP u32 =
                                                              // 6.4MB, consumed by fine_fill
                                                              // before layer0 writes yhi
    unsigned char* xq = (unsigned char*)(ylo + (size_t)N_NODES * 128);  // N*128 u8
    unsigned char* yq = xq + (size_t)N_NODES * 128;
    float* xsc = (float*)(yq + (size_t)N_NODES * 128);        // N f32
    float* ysc = xsc + N_NODES;
    int* rowbeg = (int*)(ysc + N_NODES);                      // N i32
    int* rowend = rowbeg + N_NODES;
    int* bucketCur = rowend + N_NODES;                        // 256 i32
    unsigned short* esrc = (unsigned short*)(bucketCur + 256); // NBUCK*BCAP u16 = 3.2MB
    unsigned short* packw = esrc + NBUCK * BCAP;              // 163840 bf16
    unsigned short* Wl0p = packw;
    unsigned short* Wr0p = packw + 32768;
    unsigned short* Wl1p = packw + 65536;
    unsigned short* Wr1p = packw + 98304;
    unsigned short* Wl2p = packw + 131072;
    unsigned short* Wr2p = packw + 147456;

    // --- prep (pack W + split/quantize x + zero bucketCur) ---
    prep_kernel<<<1884, 256, 0, stream>>>(Wl0, Wr0, Wl1, Wr1, Wl2, Wr2, packw,
                                          x, xhi, xlo, xq, xsc, bucketCur);
    // --- partition edges into fixed bucket regions (coalesced) ---
    partition_kernel<<<(N_EDGES + 2047) / 2048, 256, 0, stream>>>(src, dst, bucketCur, ebuf, N_EDGES);
    // --- per-bucket: rowbeg/rowend + esrc scatter ---
    fine_fill_kernel<<<NBUCK, 256, 0, stream>>>(ebuf, bucketCur, rowbeg, rowend, esrc, N_NODES);

    const int gemmGrid = (N_NODES + 31) / 32;   // 1563

    // layer 0: x-planes -> y-planes (ReLU)
    sage_layer<128, true, true><<<gemmGrid, 256, 0, stream>>>(
        xq, xsc, xhi, xlo, rowbeg, rowend, esrc, Wl0p, Wr0p, b0,
        nullptr, yhi, ylo, yq, ysc, N_NODES);
    // layer 1: y-planes -> x-planes (ReLU)
    sage_layer<128, true, true><<<gemmGrid, 256, 0, stream>>>(
        yq, ysc, yhi, ylo, rowbeg, rowend, esrc, Wl1p, Wr1p, b1,
        nullptr, xhi, xlo, xq, xsc, N_NODES);
    // layer 2: x-planes -> out (f32, no ReLU, DOUT=64)
    sage_layer<64, false, false><<<gemmGrid, 256, 0, stream>>>(
        xq, xsc, xhi, xlo, rowbeg, rowend, esrc, Wl2p, Wr2p, b2,
        outp, nullptr, nullptr, nullptr, nullptr, N_NODES);
}

// Round 11
// 234.205 us; speedup vs baseline: 1.2507x; 1.0297x over previous
//
#include <hip/hip_runtime.h>

#define N_NODES 50000
#define N_EDGES 800000
#define NBUCK 196       // dst>>8 -> 0..195
#define BCAP 8192       // fixed ebuf region per bucket (mean 4096, sd ~64)

typedef __attribute__((ext_vector_type(8))) short short8;
typedef __attribute__((ext_vector_type(4))) float f32x4;
typedef __attribute__((ext_vector_type(8))) unsigned short ushort8v;
typedef __attribute__((ext_vector_type(16))) unsigned char uchar16;

// ---------------- helpers ----------------

__device__ inline void split_bf16(float f, unsigned short& hi, unsigned short& lo) {
    union { float f; unsigned u; } a; a.f = f;
    unsigned r = (a.u + 0x7fffu + ((a.u >> 16) & 1u)) >> 16;  // RNE to bf16
    hi = (unsigned short)r;
    union { unsigned u; float f; } b; b.u = r << 16;
    union { float f; unsigned u; } c; c.f = f - b.f;
    unsigned r2 = (c.u + 0x7fffu + ((c.u >> 16) & 1u)) >> 16;
    lo = (unsigned short)r2;
}

__device__ inline unsigned short f2bf(float f) {
    union { float f; unsigned u; } a; a.f = f;
    return (unsigned short)((a.u + 0x7fffu + ((a.u >> 16) & 1u)) >> 16);
}

__device__ inline float bf2f(unsigned short u) {
    union { unsigned u; float f; } a; a.u = (unsigned)u << 16; return a.f;
}

__device__ inline unsigned char q8(float v, float qs) {
    int qi = (int)rintf(v * qs);
    qi = qi > 127 ? 127 : (qi < -127 ? -127 : qi);
    return (unsigned char)(qi + 128);
}

// accumulate 8 biased-u8 values (uint2) scaled by s into a[0..7]
__device__ inline void acc8(float* a, uint2 w, float s) {
#pragma unroll
    for (int j = 0; j < 4; ++j) {
        a[j]     += (float)((w.x >> (8 * j)) & 255u) * s;
        a[j + 4] += (float)((w.y >> (8 * j)) & 255u) * s;
    }
}

// ---------------- prep: pack(W) + split/quantize(x) + zero bucketCur ---------
// (R10-frozen)

__global__ void prep_kernel(const float* __restrict__ W0, const float* __restrict__ W1,
                            const float* __restrict__ W2, const float* __restrict__ W3,
                            const float* __restrict__ W4, const float* __restrict__ W5,
                            unsigned short* __restrict__ wout,
                            const float* __restrict__ x, unsigned short* __restrict__ xhi,
                            unsigned short* __restrict__ xlo,
                            unsigned char* __restrict__ xq, float* __restrict__ xsc,
                            int* __restrict__ bucketCur) {
    if (blockIdx.x < 320) {
        int t = blockIdx.x * 256 + threadIdx.x;  // 0..81919
        const float* W; int D, local, half; size_t base;
        if (t < 65536) {
            int mat = t >> 14; local = t & 16383; D = 128; half = 16384;
            base = (size_t)mat * 32768;
            W = mat == 0 ? W0 : mat == 1 ? W1 : mat == 2 ? W2 : W3;
        } else {
            int m = (t - 65536) >> 13; local = (t - 65536) & 8191; D = 64; half = 8192;
            base = 131072 + (size_t)m * 16384;
            W = m == 0 ? W4 : W5;
        }
        int j = local & 7, lane = (local >> 3) & 63, ks = (local >> 9) & 3, ct = local >> 11;
        int k = ks * 32 + ((lane >> 4) << 3) + j;
        int n = (ct << 4) + (lane & 15);
        unsigned short hi, lo;
        split_bf16(W[k * D + n], hi, lo);
        wout[base + local] = hi;
        wout[base + half + local] = lo;
    } else if (blockIdx.x < 1883) {
        int t = (blockIdx.x - 320) * 256 + threadIdx.x;  // one 16-float chunk/thread
        if (t >= N_NODES * 8) return;                    // 50000*128/16 = 400000
        const float* p = x + (size_t)t * 16;
        float4 v0 = *(const float4*)(p);
        float4 v1 = *(const float4*)(p + 4);
        float4 v2 = *(const float4*)(p + 8);
        float4 v3 = *(const float4*)(p + 12);
        float vv[16] = {v0.x, v0.y, v0.z, v0.w, v1.x, v1.y, v1.z, v1.w,
                        v2.x, v2.y, v2.z, v2.w, v3.x, v3.y, v3.z, v3.w};
        // rowmax over 128 floats: 8 consecutive threads share a row (aligned)
        float m = 0.f;
#pragma unroll
        for (int j = 0; j < 16; ++j) m = fmaxf(m, fabsf(vv[j]));
        m = fmaxf(m, __shfl_xor(m, 1));
        m = fmaxf(m, __shfl_xor(m, 2));
        m = fmaxf(m, __shfl_xor(m, 4));
        float qs = m > 0.f ? 127.0f / m : 0.0f;
        uchar16 qv;
        ushort8v h0, l0, h1, l1;
#pragma unroll
        for (int j = 0; j < 16; ++j) {
            unsigned short a, b;
            split_bf16(vv[j], a, b);
            if (j < 8) { h0[j] = a; l0[j] = b; } else { h1[j - 8] = a; l1[j - 8] = b; }
            qv[j] = q8(vv[j], qs);
        }
        *(ushort8v*)(xhi + (size_t)t * 16) = h0;
        *(ushort8v*)(xhi + (size_t)t * 16 + 8) = h1;
        *(ushort8v*)(xlo + (size_t)t * 16) = l0;
        *(ushort8v*)(xlo + (size_t)t * 16 + 8) = l1;
        *(uchar16*)(xq + (size_t)t * 16) = qv;
        if ((t & 7) == 0) xsc[t >> 3] = m * (1.0f / 127.0f);
    } else {
        if (threadIdx.x < 256) bucketCur[threadIdx.x] = 0;
    }
}

// ---------------- edge partition into fixed bucket regions (R10-frozen) ------

__global__ __launch_bounds__(256) void partition_kernel(
    const int* __restrict__ src, const int* __restrict__ dst,
    int* __restrict__ bucketCur, unsigned int* __restrict__ ebuf, int E) {
    __shared__ int hist[NBUCK], binoff[NBUCK], bincur[NBUCK], runstart[NBUCK];
    __shared__ int scanbuf[256];
    __shared__ unsigned int sortbuf[2048];
    const int tid = threadIdx.x;
    const int base = blockIdx.x * 2048;
    if (tid < NBUCK) hist[tid] = 0;
    __syncthreads();
    int myb[8]; unsigned int myp[8];
#pragma unroll
    for (int i = 0; i < 8; ++i) {
        int e = base + i * 256 + tid;
        if (e < E) {
            int d = dst[e], s = src[e];
            myb[i] = d >> 8;
            myp[i] = ((unsigned)d << 16) | (unsigned)s;
            atomicAdd(&hist[myb[i]], 1);
        } else myb[i] = -1;
    }
    __syncthreads();
    int v = (tid < NBUCK) ? hist[tid] : 0;
    scanbuf[tid] = v;
    __syncthreads();
    for (int off = 1; off < 256; off <<= 1) {
        int t = (tid >= off) ? scanbuf[tid - off] : 0;
        __syncthreads();
        scanbuf[tid] += t;
        __syncthreads();
    }
    if (tid < NBUCK) {
        binoff[tid] = scanbuf[tid] - v;
        bincur[tid] = 0;
        runstart[tid] = tid * BCAP + atomicAdd(&bucketCur[tid], v);
    }
    __syncthreads();
#pragma unroll
    for (int i = 0; i < 8; ++i) {
        if (myb[i] >= 0) {
            int r = atomicAdd(&bincur[myb[i]], 1);
            sortbuf[binoff[myb[i]] + r] = myp[i];
        }
    }
    __syncthreads();
    int nloc = E - base; if (nloc > 2048) nloc = 2048;
#pragma unroll
    for (int i = 0; i < 8; ++i) {
        int idx = i * 256 + tid;
        if (idx < nloc) {
            unsigned int p = sortbuf[idx];
            int b = p >> 24;   // dst>>8
            ebuf[runstart[b] + (idx - binoff[b])] = p;
        }
    }
}

// ---------------- fine fill: per bucket -> rowbeg/rowend + esrc (R10-frozen) --

__global__ __launch_bounds__(256) void fine_fill_kernel(
    const unsigned int* __restrict__ ebuf, const int* __restrict__ bucketCur,
    int* __restrict__ rowbeg, int* __restrict__ rowend,
    unsigned short* __restrict__ esrc, int n) {
    __shared__ int cnt[256], scanbuf[256], cur[256];
    const int b = blockIdx.x, tid = threadIdx.x;
    const int nbase = b << 8;
    cnt[tid] = 0;
    __syncthreads();
    const int lo = b * BCAP, hi = lo + bucketCur[b];
    for (int k = lo + tid; k < hi; k += 256)
        atomicAdd(&cnt[(ebuf[k] >> 16) & 255], 1);
    __syncthreads();
    int v = cnt[tid];
    scanbuf[tid] = v;
    __syncthreads();
    for (int off = 1; off < 256; off <<= 1) {
        int t = (tid >= off) ? scanbuf[tid - off] : 0;
        __syncthreads();
        scanbuf[tid] += t;
        __syncthreads();
    }
    int start = lo + scanbuf[tid] - v;   // exclusive
    if (nbase + tid < n) { rowbeg[nbase + tid] = start; rowend[nbase + tid] = start + v; }
    cur[tid] = start;
    __syncthreads();
    for (int k = lo + tid; k < hi; k += 256) {
        unsigned int p = ebuf[k];
        int pos = atomicAdd(&cur[(p >> 16) & 255], 1);
        esrc[pos] = (unsigned short)(p & 0xFFFFu);
    }
}

// ---------------- fused SAGE layer: 512 threads, 1 row per gather group ------
// R11: R10's fused layer showed occ 36%, Mfma 6%, HBM 20% -> latency-bound
// with a barrier critical path = max over groups of TWO rows' degrees.
// 512 thr = 32 gather groups, ONE row each: critical chain = max single
// degree (~28) vs max pair (~50) => ~45% shorter Phase B; 2x waves/CU
// (thread-capped 4 blocks = 32 waves if VGPR<=64). Phase C spreads over 8
// waves: DOUT=128: col-tile = wave (CPW=1); DOUT=64: col-tile = wave&3,
// rt = wave>>2. Per-output MFMA order identical to R10 -> bit-identical.
// (512,6): VGPR cap ~85 >> est. ~60 live -> no spill regime (R3 lesson).

template <int DOUT, bool RELU, bool SPLIT_OUT>
__global__ __launch_bounds__(512, 6) void sage_layer(
    const unsigned char* __restrict__ Hq, const float* __restrict__ Hsc,
    const unsigned short* __restrict__ Hhi, const unsigned short* __restrict__ Hlo,
    const int* __restrict__ rowbeg, const int* __restrict__ rowend,
    const unsigned short* __restrict__ esrc,
    const unsigned short* __restrict__ B1p, const unsigned short* __restrict__ B2p,
    const float* __restrict__ bias, float* __restrict__ outf,
    unsigned short* __restrict__ outhi, unsigned short* __restrict__ outlo,
    unsigned char* __restrict__ outq, float* __restrict__ outsc, int M) {
    constexpr int K = 128, BM = 32, KS = 4, CT = DOUT / 16;
    constexpr int PITCH = K + 8;
    constexpr int HALF = CT * KS * 512;
    constexpr bool SPLITRT = (CT == 4);     // 8 waves > col tiles -> split rt
    constexpr int RTN = SPLITRT ? 1 : 2;    // row-tiles handled per wave
    __shared__ unsigned short As[3][BM * PITCH];  // [agg-hi, self-hi, self-lo]
    __shared__ float wmax[BM][8];

    const int tid = threadIdx.x;
    const int r0 = blockIdx.x * BM;

    // ---- Phase A: stage self hi/lo rows (coalesced; 1 chunk/thread/plane) ----
    const unsigned short* __restrict__ srcs[2] = {Hhi, Hlo};
#pragma unroll
    for (int s = 0; s < 2; ++s) {
        int row = tid >> 4;                  // 0..31
        int c8 = (tid & 15) * 8;
        int grow = r0 + row; if (grow >= M) grow = M - 1;
        *(ushort8v*)(&As[s + 1][row * PITCH + c8]) =
            *(const ushort8v*)(srcs[s] + (size_t)grow * K + c8);
    }

    // ---- Phase B: int8 gather-mean into As[0] (R7 loop body, 1 row/group) ---
    {
        const int g16 = tid >> 4, l16 = tid & 15;   // g16: 0..31 = row
        const unsigned char* __restrict__ Hb = Hq + l16 * 8;
        int node = r0 + g16; if (node >= M) node = M - 1;  // pad: harmless dup
        int beg = rowbeg[node], end = rowend[node];
        float a0[8] = {0,0,0,0,0,0,0,0}, a1[8] = {0,0,0,0,0,0,0,0};
        float sacc = 0.f;
        int k = beg;
        for (; k + 6 <= end; k += 6) {
            int e0 = esrc[k],     e1 = esrc[k + 1], e2 = esrc[k + 2];
            int e3 = esrc[k + 3], e4 = esrc[k + 4], e5 = esrc[k + 5];
            uint2 w0 = *(const uint2*)(Hb + (size_t)e0 * 128);
            uint2 w1 = *(const uint2*)(Hb + (size_t)e1 * 128);
            uint2 w2 = *(const uint2*)(Hb + (size_t)e2 * 128);
            uint2 w3 = *(const uint2*)(Hb + (size_t)e3 * 128);
            uint2 w4 = *(const uint2*)(Hb + (size_t)e4 * 128);
            uint2 w5 = *(const uint2*)(Hb + (size_t)e5 * 128);
            float s0 = Hsc[e0], s1 = Hsc[e1], s2 = Hsc[e2];
            float s3 = Hsc[e3], s4 = Hsc[e4], s5 = Hsc[e5];
            acc8(a0, w0, s0); acc8(a1, w1, s1); acc8(a0, w2, s2);
            acc8(a1, w3, s3); acc8(a0, w4, s4); acc8(a1, w5, s5);
            sacc += s0 + s1 + s2 + s3 + s4 + s5;
        }
        for (; k + 2 <= end; k += 2) {
            int e0 = esrc[k], e1 = esrc[k + 1];
            uint2 w0 = *(const uint2*)(Hb + (size_t)e0 * 128);
            uint2 w1 = *(const uint2*)(Hb + (size_t)e1 * 128);
            float s0 = Hsc[e0], s1 = Hsc[e1];
            acc8(a0, w0, s0); acc8(a1, w1, s1);
            sacc += s0 + s1;
        }
        if (k < end) {
            int e0 = esrc[k];
            uint2 w0 = *(const uint2*)(Hb + (size_t)e0 * 128);
            float s0 = Hsc[e0];
            acc8(a0, w0, s0);
            sacc += s0;
        }
        float inv = (end > beg) ? 1.0f / (float)(end - beg) : 0.0f;
        ushort8v mh;
#pragma unroll
        for (int j = 0; j < 8; ++j)
            mh[j] = f2bf((a0[j] + a1[j] - 128.0f * sacc) * inv);
        *(ushort8v*)(&As[0][g16 * PITCH + l16 * 8]) = mh;
    }
    __syncthreads();

    // ---- Phase C: dual GEMM via MFMA over 8 waves ----
    const int wave = tid >> 6, lane = tid & 63;
    const int rl = lane & 15, quad = lane >> 4;
    const int ct = SPLITRT ? (wave & 3) : wave;   // column tile
    const int rt0 = SPLITRT ? (wave >> 2) : 0;    // first row tile

    f32x4 acc[RTN];
    {
        float bv = bias[ct * 16 + rl];
#pragma unroll
        for (int ri = 0; ri < RTN; ++ri) acc[ri] = (f32x4){bv, bv, bv, bv};
    }

#pragma unroll
    for (int ks = 0; ks < KS; ++ks) {
        short8 a_ag[RTN], a_sh[RTN][2];
#pragma unroll
        for (int ri = 0; ri < RTN; ++ri) {
            int rt = rt0 + ri;
            int off = (rt * 16 + rl) * PITCH + ks * 32 + quad * 8;
            a_ag[ri]    = *(const short8*)(&As[0][off]);
            a_sh[ri][0] = *(const short8*)(&As[1][off]);
            a_sh[ri][1] = *(const short8*)(&As[2][off]);
        }
        size_t boff = (((size_t)ct * KS + ks) * 64 + lane) * 8;
        short8 b1h = *(const short8*)(B1p + boff);
        short8 b1l = *(const short8*)(B1p + HALF + boff);
        short8 b2h = *(const short8*)(B2p + boff);
        short8 b2l = *(const short8*)(B2p + HALF + boff);
#pragma unroll
        for (int ri = 0; ri < RTN; ++ri) {
            acc[ri] = __builtin_amdgcn_mfma_f32_16x16x32_bf16(a_ag[ri],    b1h, acc[ri], 0, 0, 0);
            acc[ri] = __builtin_amdgcn_mfma_f32_16x16x32_bf16(a_ag[ri],    b1l, acc[ri], 0, 0, 0);
            acc[ri] = __builtin_amdgcn_mfma_f32_16x16x32_bf16(a_sh[ri][0], b2h, acc[ri], 0, 0, 0);
            acc[ri] = __builtin_amdgcn_mfma_f32_16x16x32_bf16(a_sh[ri][0], b2l, acc[ri], 0, 0, 0);
            acc[ri] = __builtin_amdgcn_mfma_f32_16x16x32_bf16(a_sh[ri][1], b2h, acc[ri], 0, 0, 0);
        }
    }

    // ---- apply ReLU once, in-register ----
    if (RELU) {
#pragma unroll
        for (int ri = 0; ri < RTN; ++ri)
#pragma unroll
            for (int r = 0; r < 4; ++r)
                acc[ri][r] = fmaxf(acc[ri][r], 0.f);
    }

    float qsc[RTN][4];
    if constexpr (SPLIT_OUT) {
        // per-row abs-max: reduce over the 16 lanes (cols) of this col-tile,
        // then across the 8 waves (col-tiles) via LDS. fmax exact -> scales
        // identical to R10's.
        float lm[RTN][4];
#pragma unroll
        for (int ri = 0; ri < RTN; ++ri)
#pragma unroll
            for (int r = 0; r < 4; ++r) lm[ri][r] = fabsf(acc[ri][r]);
#pragma unroll
        for (int off = 1; off < 16; off <<= 1)
#pragma unroll
            for (int ri = 0; ri < RTN; ++ri)
#pragma unroll
                for (int r = 0; r < 4; ++r)
                    lm[ri][r] = fmaxf(lm[ri][r], __shfl_xor(lm[ri][r], off));
        if (rl == 0) {
#pragma unroll
            for (int ri = 0; ri < RTN; ++ri)
#pragma unroll
                for (int r = 0; r < 4; ++r)
                    wmax[(rt0 + ri) * 16 + quad * 4 + r][wave] = lm[ri][r];
        }
        __syncthreads();
#pragma unroll
        for (int ri = 0; ri < RTN; ++ri)
#pragma unroll
            for (int r = 0; r < 4; ++r) {
                int row = (rt0 + ri) * 16 + quad * 4 + r;
                float rm = fmaxf(fmaxf(fmaxf(wmax[row][0], wmax[row][1]),
                                       fmaxf(wmax[row][2], wmax[row][3])),
                                 fmaxf(fmaxf(wmax[row][4], wmax[row][5]),
                                       fmaxf(wmax[row][6], wmax[row][7])));
                qsc[ri][r] = rm > 0.f ? 127.0f / rm : 0.0f;
                if (wave == 0 && rl == 0) {
                    int rr = r0 + row;
                    if (rr < M) outsc[rr] = rm * (1.0f / 127.0f);
                }
            }
    }

    // ---- epilogue: C/D layout col=lane&15, row=quad*4+reg ----
#pragma unroll
    for (int ri = 0; ri < RTN; ++ri) {
        int rt = rt0 + ri;
        int col = ct * 16 + rl;
        int rowb = r0 + rt * 16 + quad * 4;
#pragma unroll
        for (int r = 0; r < 4; ++r) {
            int rr = rowb + r;
            if (rr < M) {
                float vv = acc[ri][r];
                if (SPLIT_OUT) {
                    unsigned short h, l;
                    split_bf16(vv, h, l);
                    outhi[(size_t)rr * DOUT + col] = h;
                    outlo[(size_t)rr * DOUT + col] = l;
                    outq[(size_t)rr * DOUT + col] = q8(vv, qsc[ri][r]);
                } else {
                    outf[(size_t)rr * DOUT + col] = vv;
                }
            }
        }
    }
}

// ---------------- launch ----------------

extern "C" void kernel_launch(void* const* d_in, const int* in_sizes, int n_in,
                              void* d_out, int out_size, void* d_ws, size_t ws_size,
                              hipStream_t stream) {
    const float* x   = (const float*)d_in[0];
    const int* eidx  = (const int*)d_in[1];
    const int* src   = eidx;             // edge_index[0]
    const int* dst   = eidx + N_EDGES;   // edge_index[1]
    const float* Wl0 = (const float*)d_in[2];
    const float* b0  = (const float*)d_in[3];
    const float* Wr0 = (const float*)d_in[4];
    const float* Wl1 = (const float*)d_in[5];
    const float* b1  = (const float*)d_in[6];
    const float* Wr1 = (const float*)d_in[7];
    const float* Wl2 = (const float*)d_in[8];
    const float* b2  = (const float*)d_in[9];
    const float* Wr2 = (const float*)d_in[10];
    float* outp = (float*)d_out;

    // workspace (~70 MB): ping-pong plane sets + fixed-region CSR scratch
    unsigned short* xhi  = (unsigned short*)d_ws;             // N*128 u16 each
    unsigned short* xlo  = xhi + (size_t)N_NODES * 128;
    unsigned short* yhi  = xlo + (size_t)N_NODES * 128;
    unsigned short* ylo  = yhi + (size_t)N_NODES * 128;
    unsigned int* ebuf = (unsigned int*)yhi;                  // ALIAS: NBUCK*BCAP u32 =
                                                              // 6.4MB, consumed by fine_fill
                                                              // before layer0 writes yhi
    unsigned char* xq = (unsigned char*)(ylo + (size_t)N_NODES * 128);  // N*128 u8
    unsigned char* yq = xq + (size_t)N_NODES * 128;
    float* xsc = (float*)(yq + (size_t)N_NODES * 128);        // N f32
    float* ysc = xsc + N_NODES;
    int* rowbeg = (int*)(ysc + N_NODES);                      // N i32
    int* rowend = rowbeg + N_NODES;
    int* bucketCur = rowend + N_NODES;                        // 256 i32
    unsigned short* esrc = (unsigned short*)(bucketCur + 256); // NBUCK*BCAP u16 = 3.2MB
    unsigned short* packw = esrc + NBUCK * BCAP;              // 163840 bf16
    unsigned short* Wl0p = packw;
    unsigned short* Wr0p = packw + 32768;
    unsigned short* Wl1p = packw + 65536;
    unsigned short* Wr1p = packw + 98304;
    unsigned short* Wl2p = packw + 131072;
    unsigned short* Wr2p = packw + 147456;

    // --- prep (pack W + split/quantize x + zero bucketCur) ---
    prep_kernel<<<1884, 256, 0, stream>>>(Wl0, Wr0, Wl1, Wr1, Wl2, Wr2, packw,
                                          x, xhi, xlo, xq, xsc, bucketCur);
    // --- partition edges into fixed bucket regions (coalesced) ---
    partition_kernel<<<(N_EDGES + 2047) / 2048, 256, 0, stream>>>(src, dst, bucketCur, ebuf, N_EDGES);
    // --- per-bucket: rowbeg/rowend + esrc scatter ---
    fine_fill_kernel<<<NBUCK, 256, 0, stream>>>(ebuf, bucketCur, rowbeg, rowend, esrc, N_NODES);

    const int gemmGrid = (N_NODES + 31) / 32;   // 1563

    // layer 0: x-planes -> y-planes (ReLU)
    sage_layer<128, true, true><<<gemmGrid, 512, 0, stream>>>(
        xq, xsc, xhi, xlo, rowbeg, rowend, esrc, Wl0p, Wr0p, b0,
        nullptr, yhi, ylo, yq, ysc, N_NODES);
    // layer 1: y-planes -> x-planes (ReLU)
    sage_layer<128, true, true><<<gemmGrid, 512, 0, stream>>>(
        yq, ysc, yhi, ylo, rowbeg, rowend, esrc, Wl1p, Wr1p, b1,
        nullptr, xhi, xlo, xq, xsc, N_NODES);
    // layer 2: x-planes -> out (f32, no ReLU, DOUT=64)
    sage_layer<64, false, false><<<gemmGrid, 512, 0, stream>>>(
        xq, xsc, xhi, xlo, rowbeg, rowend, esrc, Wl2p, Wr2p, b2,
        outp, nullptr, nullptr, nullptr, nullptr, N_NODES);
}